// Round 13
// baseline (991.562 us; speedup 1.0000x reference)
//
#include <hip/hip_runtime.h>
#include <hip/hip_fp16.h>

// ---------------------------------------------------------------------------
// GIN (5 layers) + BN + graph pooling + MLP head.
// R13: k_mlp rewritten on MFMA (v_mfma_f32_16x16x32_f16). Per 64-node tile:
//      two 64x64x64 GEMMs = 8 mfma/wave/matvec. Weights pre-transposed to
//      fp16 [n][k] in k_prep (fragment loads = contiguous 16B); A-fragments
//      load directly from global fp16 activations (phase-A staging deleted);
//      t/v round-trip through a 9KB padded LDS fp16 tile (stride 72).
//      Phase C: 8-ch octets, raw uint4 fp16 stores (1KB/instr coalesced).
//      R12 (762us) was s_load-latency bound in the matvec k-loop (~5x VALU
//      floor). Rest identical to R12.
// ---------------------------------------------------------------------------

#define SCAN_ELEMS 1024

typedef _Float16 half8v __attribute__((ext_vector_type(8)));
typedef float float4v __attribute__((ext_vector_type(4)));

__device__ __forceinline__ unsigned short f2h(float f) {
    return __half_as_ushort(__float2half_rn(f));
}
__device__ __forceinline__ float h2f(unsigned short s) {
    return __half2float(__ushort_as_half(s));
}

// Edge-only histogram + rank (atomic returns slot)
__global__ __launch_bounds__(256) void k_hist(const int* __restrict__ dst, int E,
        int* __restrict__ cnt_node, int* __restrict__ rank_) {
    int i = blockIdx.x * blockDim.x + threadIdx.x;
    if (i < E) rank_[i] = atomicAdd(&cnt_node[dst[i]], 1);
}

// Node prep: x -> fp16 padded 16ch, graph counts, weight transpose fp32->fp16
__global__ __launch_bounds__(256) void k_prep(const float* __restrict__ x,
        unsigned short* __restrict__ x16h, const int* __restrict__ batch,
        int* __restrict__ cnt_graph, int N,
        const float* __restrict__ W1a, const float* __restrict__ W1b,
        const float* __restrict__ Wa, const float* __restrict__ Wb,
        unsigned short* __restrict__ W1aT, unsigned short* __restrict__ W1bT,
        unsigned short* __restrict__ WaT, unsigned short* __restrict__ WbT) {
    int i = blockIdx.x * blockDim.x + threadIdx.x;
    if (i < N) {
        atomicAdd(&cnt_graph[batch[i]], 1);
#pragma unroll
        for (int k = 0; k < 11; ++k) x16h[i * 16 + k] = f2h(x[i * 11 + k]);
#pragma unroll
        for (int k = 11; k < 16; ++k) x16h[i * 16 + k] = 0;
    }
    if (i < 2048) {                 // W1aT [n=64][k=32], k<11 valid
        int n = i >> 5, k = i & 31;
        W1aT[i] = (k < 11) ? f2h(W1a[k * 64 + n]) : (unsigned short)0;
    }
    if (i < 4096) {                 // W1bT [n=64][k=64]
        int n = i >> 6, k = i & 63;
        W1bT[i] = f2h(W1b[k * 64 + n]);
    }
    if (i < 16384) {                // WaT/WbT [l][n=64][k=64]
        int l = i >> 12, r = i & 4095, n = r >> 6, k = r & 63;
        WaT[(size_t)l * 4096 + n * 64 + k] = f2h(Wa[(size_t)l * 4096 + k * 64 + n]);
        WbT[(size_t)l * 4096 + n * 64 + k] = f2h(Wb[(size_t)l * 4096 + k * 64 + n]);
    }
}

__global__ __launch_bounds__(256) void k_scan1(const int* __restrict__ cnt, int n,
        int* __restrict__ rp, int* __restrict__ bsum) {
    __shared__ int sdata[256];
    int t = threadIdx.x;
    int base = blockIdx.x * SCAN_ELEMS + t * 4;
    int v0 = (base + 0 < n) ? cnt[base + 0] : 0;
    int v1 = (base + 1 < n) ? cnt[base + 1] : 0;
    int v2 = (base + 2 < n) ? cnt[base + 2] : 0;
    int v3 = (base + 3 < n) ? cnt[base + 3] : 0;
    int tsum = v0 + v1 + v2 + v3;
    sdata[t] = tsum;
    __syncthreads();
    for (int off = 1; off < 256; off <<= 1) {
        int val = (t >= off) ? sdata[t - off] : 0;
        __syncthreads();
        sdata[t] += val;
        __syncthreads();
    }
    int excl = sdata[t] - tsum;
    if (t == 255) bsum[blockIdx.x] = sdata[255];
    if (base + 0 < n) rp[base + 0] = excl;
    if (base + 1 < n) rp[base + 1] = excl + v0;
    if (base + 2 < n) rp[base + 2] = excl + v0 + v1;
    if (base + 3 < n) rp[base + 3] = excl + v0 + v1 + v2;
}

__global__ __launch_bounds__(128) void k_scan2(const int* __restrict__ bsum, int nb,
        int* __restrict__ boffs) {
    __shared__ int sd[128];
    int t = threadIdx.x;
    int v = (t < nb) ? bsum[t] : 0;
    sd[t] = v;
    __syncthreads();
    for (int off = 1; off < 128; off <<= 1) {
        int val = (t >= off) ? sd[t - off] : 0;
        __syncthreads();
        sd[t] += val;
        __syncthreads();
    }
    if (t < nb) boffs[t] = sd[t] - v;
}

__global__ __launch_bounds__(256) void k_scan3(int* __restrict__ rp, int n,
        const int* __restrict__ boffs, int E) {
    int i = blockIdx.x * blockDim.x + threadIdx.x;
    if (i < n) rp[i] += boffs[i / SCAN_ELEMS];
    if (i == 0) rp[n] = E;
}

__global__ __launch_bounds__(256) void k_fill(const int* __restrict__ src,
        const int* __restrict__ dst, const int* __restrict__ rank_, int E,
        const int* __restrict__ rp, int* __restrict__ col) {
    int e = blockIdx.x * blockDim.x + threadIdx.x;
    if (e < E) {
        __builtin_nontemporal_store(src[e], &col[rp[dst[e]] + rank_[e]]);
    }
}

// Layer-1 gather in padded 11->16 dim fp16 space: wave = 1 node, fp16 out.
__global__ __launch_bounds__(256, 8) void k_gather16(
        const unsigned short* __restrict__ x16h, unsigned short* __restrict__ h16h,
        const int* __restrict__ rp, const int* __restrict__ col, int N) {
    int lane = threadIdx.x & 63, wv = threadIdx.x >> 6;
    int n = blockIdx.x * 4 + wv;
    if (n >= N) return;
    int sub = lane >> 4, c = lane & 15;
    int start = rp[n], end = rp[n + 1];
    float s0 = 0.f, s1 = 0.f, s2 = 0.f, s3 = 0.f;
    int eb = start;
    for (; eb + 16 <= end; eb += 16) {
        int j0 = col[eb + sub];
        int j1 = col[eb + 4 + sub];
        int j2 = col[eb + 8 + sub];
        int j3 = col[eb + 12 + sub];
        s0 += h2f(x16h[(size_t)j0 * 16 + c]);
        s1 += h2f(x16h[(size_t)j1 * 16 + c]);
        s2 += h2f(x16h[(size_t)j2 * 16 + c]);
        s3 += h2f(x16h[(size_t)j3 * 16 + c]);
    }
    for (; eb + 4 <= end; eb += 4) {
        int j0 = col[eb + sub];
        s0 += h2f(x16h[(size_t)j0 * 16 + c]);
    }
    for (int e = eb + sub; e < end; e += 4) {
        s1 += h2f(x16h[(size_t)col[e] * 16 + c]);
    }
    float s = (s0 + s1) + (s2 + s3);
    s += __shfl_xor(s, 16);
    s += __shfl_xor(s, 32);
    if (lane < 16) {
        h16h[(size_t)n * 16 + lane] = f2h(s + h2f(x16h[(size_t)n * 16 + lane]));
    }
}

// Gather (layers 2-5): one wave per node, lane = channel, fp16 in/out.
__global__ __launch_bounds__(256, 8) void k_gather(
        const unsigned short* __restrict__ vin, unsigned short* __restrict__ aggh,
        const int* __restrict__ rp, const int* __restrict__ col,
        const float* __restrict__ ab_prev, int N) {
    int lane = threadIdx.x & 63, wv = threadIdx.x >> 6;
    int n = blockIdx.x * 4 + wv;
    if (n >= N) return;
    float a = ab_prev[lane];
    float b = ab_prev[64 + lane];
    int start = rp[n], end = rp[n + 1];
    float s[16];
#pragma unroll
    for (int u = 0; u < 16; ++u) s[u] = 0.f;
    s[0] = h2f(vin[(size_t)n * 64 + lane]);
    int e = start;
    for (; e + 16 <= end; e += 16) {
        int j[16];
#pragma unroll
        for (int u = 0; u < 16; ++u) j[u] = col[e + u];
#pragma unroll
        for (int u = 0; u < 16; ++u)
            s[u] += h2f(vin[(size_t)j[u] * 64 + lane]);
    }
    for (; e + 4 <= end; e += 4) {
        int j0 = col[e + 0], j1 = col[e + 1], j2 = col[e + 2], j3 = col[e + 3];
        s[0] += h2f(vin[(size_t)j0 * 64 + lane]);
        s[1] += h2f(vin[(size_t)j1 * 64 + lane]);
        s[2] += h2f(vin[(size_t)j2 * 64 + lane]);
        s[3] += h2f(vin[(size_t)j3 * 64 + lane]);
    }
    for (; e < end; ++e) s[0] += h2f(vin[(size_t)col[e] * 64 + lane]);
#pragma unroll
    for (int u = 8; u > 0; u >>= 1)
#pragma unroll
        for (int v2 = 0; v2 < u; ++v2) s[v2] += s[v2 + u];
    float h2 = fmaf(a, s[0], b * (float)(1 + end - start));
    aggh[(size_t)n * 64 + lane] = f2h(h2);
}

// MLP via MFMA: one block = one 64-node tile; two 64x64x64 fp16 GEMMs.
// A[m=lane&15][k=quad*8+j] from global fp16 activations; B[k][n=lane&15]
// from pre-transposed fp16 weights [n][k]; D: col=lane&15, row=quad*4+reg.
template <bool FIRST>
__global__ __launch_bounds__(256, 4) void k_mlp(
        const unsigned short* __restrict__ hin,   // FIRST: h16h (Nx16) else aggh (Nx64)
        unsigned short* __restrict__ vout,
        const int* __restrict__ batch,
        const unsigned short* __restrict__ WaT,   // FIRST: [64][32] else [64][64]
        const float* __restrict__ ba,
        const unsigned short* __restrict__ WbT,   // [64][64]
        const float* __restrict__ bb,
        float* __restrict__ Sg, float* __restrict__ bnpart,
        int N) {
    __shared__ alignas(16) unsigned short tt[64 * 72];   // padded fp16 tile
    const int tid = threadIdx.x;
    const int lane = tid & 63;
    const int wv = tid >> 6;
    const int n0 = blockIdx.x * 64;
    const int l15 = lane & 15;
    const int quad = lane >> 4;
    const int mnode = wv * 16 + l15;          // A-fragment row (node in tile)

    float4v acc[4];

    // ---- matvec1: t = relu(h @ Wa + ba) ----
    {
        half8v a0, a1;
#pragma unroll
        for (int j = 0; j < 8; ++j) { a0[j] = (_Float16)0.f; a1[j] = (_Float16)0.f; }
        if (FIRST) {
            if (n0 + mnode < N && quad < 2)
                a0 = *(const half8v*)(hin + (size_t)(n0 + mnode) * 16 + quad * 8);
        } else {
            if (n0 + mnode < N) {
                a0 = *(const half8v*)(hin + (size_t)(n0 + mnode) * 64 + quad * 8);
                a1 = *(const half8v*)(hin + (size_t)(n0 + mnode) * 64 + 32 + quad * 8);
            }
        }
#pragma unroll
        for (int nt = 0; nt < 4; ++nt) {
            int bn = nt * 16 + l15;
            float4v c = {0.f, 0.f, 0.f, 0.f};
            if (FIRST) {
                half8v b0 = *(const half8v*)(WaT + bn * 32 + quad * 8);
                c = __builtin_amdgcn_mfma_f32_16x16x32_f16(a0, b0, c, 0, 0, 0);
            } else {
                half8v b0 = *(const half8v*)(WaT + bn * 64 + quad * 8);
                half8v b1 = *(const half8v*)(WaT + bn * 64 + 32 + quad * 8);
                c = __builtin_amdgcn_mfma_f32_16x16x32_f16(a0, b0, c, 0, 0, 0);
                c = __builtin_amdgcn_mfma_f32_16x16x32_f16(a1, b1, c, 0, 0, 0);
            }
            acc[nt] = c;
        }
    }
    // bias + relu -> tt (fp16, [node][72])
#pragma unroll
    for (int nt = 0; nt < 4; ++nt) {
        int c = nt * 16 + l15;
        float bav = ba[c];
#pragma unroll
        for (int r = 0; r < 4; ++r) {
            int node = wv * 16 + quad * 4 + r;
            tt[node * 72 + c] = f2h(fmaxf(acc[nt][r] + bav, 0.f));
        }
    }
    __syncthreads();

    // ---- matvec2: v = relu(t @ Wb + bb) ----
    {
        half8v a0 = *(const half8v*)(tt + mnode * 72 + quad * 8);
        half8v a1 = *(const half8v*)(tt + mnode * 72 + 32 + quad * 8);
        __syncthreads();   // all tt reads done before overwrite
#pragma unroll
        for (int nt = 0; nt < 4; ++nt) {
            int bn = nt * 16 + l15;
            half8v b0 = *(const half8v*)(WbT + bn * 64 + quad * 8);
            half8v b1 = *(const half8v*)(WbT + bn * 64 + 32 + quad * 8);
            float4v c = {0.f, 0.f, 0.f, 0.f};
            c = __builtin_amdgcn_mfma_f32_16x16x32_f16(a0, b0, c, 0, 0, 0);
            c = __builtin_amdgcn_mfma_f32_16x16x32_f16(a1, b1, c, 0, 0, 0);
            acc[nt] = c;
        }
#pragma unroll
        for (int nt = 0; nt < 4; ++nt) {
            int c = nt * 16 + l15;
            float bbv = bb[c];
#pragma unroll
            for (int r = 0; r < 4; ++r) {
                int node = wv * 16 + quad * 4 + r;
                tt[node * 72 + c] = f2h(fmaxf(acc[nt][r] + bbv, 0.f));
            }
        }
    }
    __syncthreads();

    // ---- phase C: coalesced fp16 store + BN stats + graph pooling ----
    {
        int q8 = lane & 7;            // channel octet
        int ng = lane >> 3;           // node subgroup 0..7
        int base_nt = wv * 16;
        float bsf[8], bqf[8];
#pragma unroll
        for (int j = 0; j < 8; ++j) { bsf[j] = 0.f; bqf[j] = 0.f; }

        bool full = (n0 + base_nt + 15) < N;            // wave-uniform
        int gf = 0, gl = -1;
        if (full) { gf = batch[n0 + base_nt]; gl = batch[n0 + base_nt + 15]; }

        if (full && gf == gl) {
            float pf[8];
#pragma unroll
            for (int j = 0; j < 8; ++j) pf[j] = 0.f;
#pragma unroll
            for (int s2 = 0; s2 < 2; ++s2) {
                int nt = base_nt + s2 * 8 + ng;
                uint4 u = *(const uint4*)(tt + nt * 72 + q8 * 8);
                *(uint4*)(vout + (size_t)(n0 + nt) * 64 + q8 * 8) = u;
                const unsigned short* up = (const unsigned short*)&u;
#pragma unroll
                for (int j = 0; j < 8; ++j) {
                    float v = h2f(up[j]);
                    bsf[j] += v; bqf[j] += v * v; pf[j] += v;
                }
            }
#pragma unroll
            for (int off = 8; off < 64; off <<= 1)
#pragma unroll
                for (int j = 0; j < 8; ++j) pf[j] += __shfl_xor(pf[j], off);
            if (ng == 0) {
#pragma unroll
                for (int j = 0; j < 8; ++j)
                    atomicAdd(&Sg[gf * 64 + q8 * 8 + j], pf[j]);
            }
        } else {
            float pf[8];
#pragma unroll
            for (int j = 0; j < 8; ++j) pf[j] = 0.f;
            int curg = -1;
#pragma unroll
            for (int s2 = 0; s2 < 2; ++s2) {
                int nt = base_nt + s2 * 8 + ng;
                int n = n0 + nt;
                if (n < N) {
                    uint4 u = *(const uint4*)(tt + nt * 72 + q8 * 8);
                    *(uint4*)(vout + (size_t)n * 64 + q8 * 8) = u;
                    const unsigned short* up = (const unsigned short*)&u;
                    int g = batch[n];
                    if (g != curg) {
                        if (curg >= 0) {
#pragma unroll
                            for (int j = 0; j < 8; ++j)
                                atomicAdd(&Sg[curg * 64 + q8 * 8 + j], pf[j]);
                        }
                        curg = g;
#pragma unroll
                        for (int j = 0; j < 8; ++j) pf[j] = 0.f;
                    }
#pragma unroll
                    for (int j = 0; j < 8; ++j) {
                        float v = h2f(up[j]);
                        bsf[j] += v; bqf[j] += v * v; pf[j] += v;
                    }
                }
            }
            if (curg >= 0) {
#pragma unroll
                for (int j = 0; j < 8; ++j)
                    atomicAdd(&Sg[curg * 64 + q8 * 8 + j], pf[j]);
            }
        }
#pragma unroll
        for (int off = 8; off < 64; off <<= 1)
#pragma unroll
            for (int j = 0; j < 8; ++j) {
                bsf[j] += __shfl_xor(bsf[j], off);
                bqf[j] += __shfl_xor(bqf[j], off);
            }
        if (ng == 0) {
            float* bkt = bnpart + (blockIdx.x & 31) * 128;
#pragma unroll
            for (int j = 0; j < 8; ++j) {
                atomicAdd(&bkt[q8 * 8 + j], bsf[j]);
                atomicAdd(&bkt[64 + q8 * 8 + j], bqf[j]);
            }
        }
    }
}

__global__ void k_bnstat(const float* __restrict__ bnpart,
        const float* __restrict__ gamma, const float* __restrict__ beta,
        float* __restrict__ a, float* __restrict__ b, int N) {
    int c = threadIdx.x;  // 64 threads
    float s = 0.f, q = 0.f;
    for (int i = 0; i < 32; ++i) { s += bnpart[i * 128 + c]; q += bnpart[i * 128 + 64 + c]; }
    float invN = 1.0f / (float)N;
    float mu = s * invN;
    float var = q * invN - mu * mu;
    float ac = gamma[c] * rsqrtf(var + 1e-5f);
    a[c] = ac;
    b[c] = beta[c] - mu * ac;
}

// Head: z[g,320] = concat_l (a_l*S_l[g] + b_l*cnt[g]); out = relu(z@fc1+b)@fc2+b
__global__ __launch_bounds__(256) void k_final(
        const float* __restrict__ S, const float* __restrict__ ab,
        const int* __restrict__ cntg,
        const float* __restrict__ fc1W, const float* __restrict__ fc1b,
        const float* __restrict__ fc2W, const float* __restrict__ fc2b,
        float* __restrict__ out, int G) {
    __shared__ float zbuf[4][320];
    int tid = threadIdx.x;
    int lane = tid & 63, wv = tid >> 6;
    int g = blockIdx.x * 4 + wv;
    if (g >= G) return;
    float cf = (float)cntg[g];
#pragma unroll
    for (int l = 0; l < 5; ++l) {
        float a = ab[l * 128 + lane];
        float b = ab[l * 128 + 64 + lane];
        zbuf[wv][l * 64 + lane] = a * S[((size_t)l * G + g) * 64 + lane] + b * cf;
    }
    float acc = fc1b[lane];
    for (int k = 0; k < 320; ++k) acc += zbuf[wv][k] * fc1W[k * 64 + lane];
    float t = fmaxf(acc, 0.f);
    float r = t * fc2W[lane];
#pragma unroll
    for (int off = 32; off >= 1; off >>= 1) r += __shfl_xor(r, off);
    if (lane == 0) out[g] = r + fc2b[0];
}

extern "C" void kernel_launch(void* const* d_in, const int* in_sizes, int n_in,
                              void* d_out, int out_size, void* d_ws, size_t ws_size,
                              hipStream_t stream) {
    const float* x    = (const float*)d_in[0];
    const int*   ei   = (const int*)d_in[1];
    const int*   batch= (const int*)d_in[2];
    const float* W1a  = (const float*)d_in[3];
    const float* b1a  = (const float*)d_in[4];
    const float* W1b  = (const float*)d_in[5];
    const float* b1b  = (const float*)d_in[6];
    const float* Wa   = (const float*)d_in[7];
    const float* ba   = (const float*)d_in[8];
    const float* Wb   = (const float*)d_in[9];
    const float* bb   = (const float*)d_in[10];
    const float* gamma= (const float*)d_in[11];
    const float* beta = (const float*)d_in[12];
    const float* fc1W = (const float*)d_in[13];
    const float* fc1b = (const float*)d_in[14];
    const float* fc2W = (const float*)d_in[15];
    const float* fc2b = (const float*)d_in[16];

    const int N = in_sizes[2];
    const int E = in_sizes[1] / 2;
    const int G = out_size;
    const int* srcp = ei;
    const int* dstp = ei + E;

    char* p = (char*)d_ws;
    auto alloc = [&](size_t bytes) {
        char* r = p;
        p += (bytes + 255) & ~size_t(255);
        return r;
    };
    unsigned short* aggh = (unsigned short*)alloc((size_t)N * 64 * 2);
    unsigned short* vb   = (unsigned short*)alloc((size_t)N * 64 * 2);
    int*   col    = (int*)  alloc((size_t)E * 4);
    int*   rank_  = (int*)  alloc((size_t)E * 4);
    int*   rp     = (int*)  alloc((size_t)(N + 1) * 4);
    unsigned short* x16h = (unsigned short*)alloc((size_t)N * 16 * 2);
    unsigned short* h16h = (unsigned short*)alloc((size_t)N * 16 * 2);
    unsigned short* W1aT = (unsigned short*)alloc(2048 * 2);
    unsigned short* W1bT = (unsigned short*)alloc(4096 * 2);
    unsigned short* WaT  = (unsigned short*)alloc((size_t)4 * 4096 * 2);
    unsigned short* WbT  = (unsigned short*)alloc((size_t)4 * 4096 * 2);
    int*   bsum   = (int*)  alloc(512);
    int*   boffs  = (int*)  alloc(512);
    float* ab     = (float*)alloc(5 * 128 * 4);
    // ---- zeroed region (single memset) ----
    char*  z0     = p;
    int*   cntn   = (int*)  alloc((size_t)N * 4);
    int*   cntg   = (int*)  alloc((size_t)G * 4);
    float* S      = (float*)alloc((size_t)5 * G * 64 * 4);
    float* bnpart = (float*)alloc((size_t)5 * 32 * 128 * 4);
    size_t zbytes = (size_t)(p - z0);

    hipMemsetAsync(z0, 0, zbytes, stream);

    int nb_e = (E + 255) / 256;
    int nb_n = (N + 255) / 256;
    int nb_scan = (N + SCAN_ELEMS - 1) / SCAN_ELEMS;
    k_hist<<<nb_e, 256, 0, stream>>>(dstp, E, cntn, rank_);
    k_prep<<<nb_n, 256, 0, stream>>>(x, x16h, batch, cntg, N,
        W1a, W1b, Wa, Wb, W1aT, W1bT, WaT, WbT);
    k_scan1<<<nb_scan, 256, 0, stream>>>(cntn, N, rp, bsum);
    k_scan2<<<1, 128, 0, stream>>>(bsum, nb_scan, boffs);
    k_scan3<<<(N + 255) / 256, 256, 0, stream>>>(rp, N, boffs, E);
    k_fill<<<nb_e, 256, 0, stream>>>(srcp, dstp, rank_, E, rp, col);

    int nb_node = (N + 3) / 4;
    int nb_tile = (N + 63) / 64;

    // Layer 1: 16-dim fp16 gather, then MFMA mlp<FIRST>
    k_gather16<<<nb_node, 256, 0, stream>>>(x16h, h16h, rp, col, N);
    k_mlp<true><<<nb_tile, 256, 0, stream>>>(h16h, vb, batch,
        W1aT, b1a, W1bT, b1b, S, bnpart, N);
    k_bnstat<<<1, 64, 0, stream>>>(bnpart, gamma, beta, ab, ab + 64, N);

    for (int l = 0; l < 4; ++l) {
        k_gather<<<nb_node, 256, 0, stream>>>(vb, aggh, rp, col,
            ab + l * 128, N);
        k_mlp<false><<<nb_tile, 256, 0, stream>>>(aggh, vb, batch,
            WaT + (size_t)l * 4096, ba + l * 64,
            WbT + (size_t)l * 4096, bb + l * 64,
            S + (size_t)(l + 1) * G * 64,
            bnpart + (size_t)(l + 1) * 32 * 128, N);
        k_bnstat<<<1, 64, 0, stream>>>(
            bnpart + (size_t)(l + 1) * 32 * 128,
            gamma + (l + 1) * 64, beta + (l + 1) * 64,
            ab + (l + 1) * 128, ab + (l + 1) * 128 + 64, N);
    }

    k_final<<<(G + 3) / 4, 256, 0, stream>>>(S, ab, cntg, fc1W, fc1b, fc2W, fc2b,
                                             (float*)d_out, G);
}

// Round 14
// 979.582 us; speedup vs baseline: 1.0122x; 1.0122x over previous
//
#include <hip/hip_runtime.h>
#include <hip/hip_fp16.h>

// ---------------------------------------------------------------------------
// GIN (5 layers) + BN + graph pooling + MLP head.
// R14: revert R13's MFMA mlp (regressed 2.4x: thin latency chain, 31% occ,
//      MfmaUtil 0.5% -- same failure family as R9's fusion). Back to R12's
//      structure (762us best). One change: k_mlp weights fp16 on the scalar
//      pipe (k_prep converts W1b/Wa/Wb to fp16, same [k][n] layout) ->
//      s_load bytes halve; unpack via v_cvt on the 87%-idle VALU.
// ---------------------------------------------------------------------------

#define SCAN_ELEMS 1024

__device__ __forceinline__ unsigned short f2h(float f) {
    return __half_as_ushort(__float2half_rn(f));
}
__device__ __forceinline__ float h2f(unsigned short s) {
    return __half2float(__ushort_as_half(s));
}

// Edge-only histogram + rank (atomic returns slot)
__global__ __launch_bounds__(256) void k_hist(const int* __restrict__ dst, int E,
        int* __restrict__ cnt_node, int* __restrict__ rank_) {
    int i = blockIdx.x * blockDim.x + threadIdx.x;
    if (i < E) rank_[i] = atomicAdd(&cnt_node[dst[i]], 1);
}

// Node prep: x -> fp16 padded 16ch, graph counts, W1b/Wa/Wb -> fp16 [k][n]
__global__ __launch_bounds__(256) void k_prep(const float* __restrict__ x,
        unsigned short* __restrict__ x16h, const int* __restrict__ batch,
        int* __restrict__ cnt_graph, int N,
        const float* __restrict__ W1b, const float* __restrict__ Wa,
        const float* __restrict__ Wb,
        unsigned short* __restrict__ W1bH, unsigned short* __restrict__ WaH,
        unsigned short* __restrict__ WbH) {
    int i = blockIdx.x * blockDim.x + threadIdx.x;
    if (i < N) {
        atomicAdd(&cnt_graph[batch[i]], 1);
#pragma unroll
        for (int k = 0; k < 11; ++k) x16h[i * 16 + k] = f2h(x[i * 11 + k]);
#pragma unroll
        for (int k = 11; k < 16; ++k) x16h[i * 16 + k] = 0;
    }
    if (i < 4096) W1bH[i] = f2h(W1b[i]);
    if (i < 16384) {
        WaH[i] = f2h(Wa[i]);
        WbH[i] = f2h(Wb[i]);
    }
}

__global__ __launch_bounds__(256) void k_scan1(const int* __restrict__ cnt, int n,
        int* __restrict__ rp, int* __restrict__ bsum) {
    __shared__ int sdata[256];
    int t = threadIdx.x;
    int base = blockIdx.x * SCAN_ELEMS + t * 4;
    int v0 = (base + 0 < n) ? cnt[base + 0] : 0;
    int v1 = (base + 1 < n) ? cnt[base + 1] : 0;
    int v2 = (base + 2 < n) ? cnt[base + 2] : 0;
    int v3 = (base + 3 < n) ? cnt[base + 3] : 0;
    int tsum = v0 + v1 + v2 + v3;
    sdata[t] = tsum;
    __syncthreads();
    for (int off = 1; off < 256; off <<= 1) {
        int val = (t >= off) ? sdata[t - off] : 0;
        __syncthreads();
        sdata[t] += val;
        __syncthreads();
    }
    int excl = sdata[t] - tsum;
    if (t == 255) bsum[blockIdx.x] = sdata[255];
    if (base + 0 < n) rp[base + 0] = excl;
    if (base + 1 < n) rp[base + 1] = excl + v0;
    if (base + 2 < n) rp[base + 2] = excl + v0 + v1;
    if (base + 3 < n) rp[base + 3] = excl + v0 + v1 + v2;
}

__global__ __launch_bounds__(128) void k_scan2(const int* __restrict__ bsum, int nb,
        int* __restrict__ boffs) {
    __shared__ int sd[128];
    int t = threadIdx.x;
    int v = (t < nb) ? bsum[t] : 0;
    sd[t] = v;
    __syncthreads();
    for (int off = 1; off < 128; off <<= 1) {
        int val = (t >= off) ? sd[t - off] : 0;
        __syncthreads();
        sd[t] += val;
        __syncthreads();
    }
    if (t < nb) boffs[t] = sd[t] - v;
}

__global__ __launch_bounds__(256) void k_scan3(int* __restrict__ rp, int n,
        const int* __restrict__ boffs, int E) {
    int i = blockIdx.x * blockDim.x + threadIdx.x;
    if (i < n) rp[i] += boffs[i / SCAN_ELEMS];
    if (i == 0) rp[n] = E;
}

__global__ __launch_bounds__(256) void k_fill(const int* __restrict__ src,
        const int* __restrict__ dst, const int* __restrict__ rank_, int E,
        const int* __restrict__ rp, int* __restrict__ col) {
    int e = blockIdx.x * blockDim.x + threadIdx.x;
    if (e < E) {
        __builtin_nontemporal_store(src[e], &col[rp[dst[e]] + rank_[e]]);
    }
}

// Layer-1 gather in padded 11->16 dim fp16 space: wave = 1 node, 4 edges per
// step (16 lanes per edge), 4-deep -> 16 edges in flight. fp32 out.
__global__ __launch_bounds__(256, 8) void k_gather16(
        const unsigned short* __restrict__ x16h, float* __restrict__ h16,
        const int* __restrict__ rp, const int* __restrict__ col, int N) {
    int lane = threadIdx.x & 63, wv = threadIdx.x >> 6;
    int n = blockIdx.x * 4 + wv;
    if (n >= N) return;
    int sub = lane >> 4, c = lane & 15;
    int start = rp[n], end = rp[n + 1];
    float s0 = 0.f, s1 = 0.f, s2 = 0.f, s3 = 0.f;
    int eb = start;
    for (; eb + 16 <= end; eb += 16) {
        int j0 = col[eb + sub];
        int j1 = col[eb + 4 + sub];
        int j2 = col[eb + 8 + sub];
        int j3 = col[eb + 12 + sub];
        s0 += h2f(x16h[(size_t)j0 * 16 + c]);
        s1 += h2f(x16h[(size_t)j1 * 16 + c]);
        s2 += h2f(x16h[(size_t)j2 * 16 + c]);
        s3 += h2f(x16h[(size_t)j3 * 16 + c]);
    }
    for (; eb + 4 <= end; eb += 4) {
        int j0 = col[eb + sub];
        s0 += h2f(x16h[(size_t)j0 * 16 + c]);
    }
    for (int e = eb + sub; e < end; e += 4) {
        s1 += h2f(x16h[(size_t)col[e] * 16 + c]);
    }
    float s = (s0 + s1) + (s2 + s3);
    s += __shfl_xor(s, 16);
    s += __shfl_xor(s, 32);
    if (lane < 16) {
        h16[(size_t)n * 16 + lane] = s + h2f(x16h[(size_t)n * 16 + lane]);
    }
}

// Gather (layers 2-5): one wave per node, lane = channel, fp16 in/out.
// s = v_n + sum_j v_j; h2 = a*s + b*(1+deg) in fp32; 16-deep load ILP.
__global__ __launch_bounds__(256, 8) void k_gather(
        const unsigned short* __restrict__ vin, unsigned short* __restrict__ aggh,
        const int* __restrict__ rp, const int* __restrict__ col,
        const float* __restrict__ ab_prev, int N) {
    int lane = threadIdx.x & 63, wv = threadIdx.x >> 6;
    int n = blockIdx.x * 4 + wv;
    if (n >= N) return;
    float a = ab_prev[lane];
    float b = ab_prev[64 + lane];
    int start = rp[n], end = rp[n + 1];
    float s[16];
#pragma unroll
    for (int u = 0; u < 16; ++u) s[u] = 0.f;
    s[0] = h2f(vin[(size_t)n * 64 + lane]);
    int e = start;
    for (; e + 16 <= end; e += 16) {
        int j[16];
#pragma unroll
        for (int u = 0; u < 16; ++u) j[u] = col[e + u];
#pragma unroll
        for (int u = 0; u < 16; ++u)
            s[u] += h2f(vin[(size_t)j[u] * 64 + lane]);
    }
    for (; e + 4 <= end; e += 4) {
        int j0 = col[e + 0], j1 = col[e + 1], j2 = col[e + 2], j3 = col[e + 3];
        s[0] += h2f(vin[(size_t)j0 * 64 + lane]);
        s[1] += h2f(vin[(size_t)j1 * 64 + lane]);
        s[2] += h2f(vin[(size_t)j2 * 64 + lane]);
        s[3] += h2f(vin[(size_t)j3 * 64 + lane]);
    }
    for (; e < end; ++e) s[0] += h2f(vin[(size_t)col[e] * 64 + lane]);
#pragma unroll
    for (int u = 8; u > 0; u >>= 1)
#pragma unroll
        for (int v2 = 0; v2 < u; ++v2) s[v2] += s[v2 + u];
    float h2 = fmaf(a, s[0], b * (float)(1 + end - start));
    aggh[(size_t)n * 64 + lane] = f2h(h2);
}

// MLP: one block = one 64-node tile. k-chunked matvecs; weights fp16 via the
// scalar pipe (uniform addresses -> s_load, v_cvt unpack). fp16 in/out.
template <bool FIRST>
__global__ __launch_bounds__(256, 4) void k_mlp(
        const void* __restrict__ aggp, unsigned short* __restrict__ vout,
        const int* __restrict__ batch,
        const float* __restrict__ W1a,            // FIRST only (fp32 [11][64])
        const unsigned short* __restrict__ WaH,   // !FIRST ([64][64] fp16)
        const float* __restrict__ ba,
        const unsigned short* __restrict__ WbH,   // [64][64] fp16
        const float* __restrict__ bb,
        float* __restrict__ Sg, float* __restrict__ bnpart,
        int N) {
    __shared__ float hb[64 * 64];
    float4* hb4 = (float4*)hb;
    const int tid = threadIdx.x;
    const int lane = tid & 63;
    const int wv = tid >> 6;
    const int n0 = blockIdx.x * 64;
    const int l15 = lane & 15;
    // wave-uniform channel base, provably uniform -> weight reads use s_load
    const int c0 = __builtin_amdgcn_readfirstlane(wv) * 16;

    float acc[16];

    if (FIRST) {
        // ---- phase A': h16 (fp32 Nx16) -> transposed LDS hs[k][node] ----
        const float* h16 = (const float*)aggp;
        float* hs = hb;
        {
            int n = tid >> 2, kq = tid & 3;
            float4 v = make_float4(0.f, 0.f, 0.f, 0.f);
            if (n0 + n < N) v = ((const float4*)h16)[(size_t)n0 * 4 + tid];
            hs[(kq * 4 + 0) * 64 + n] = v.x;
            hs[(kq * 4 + 1) * 64 + n] = v.y;
            hs[(kq * 4 + 2) * 64 + n] = v.z;
            hs[(kq * 4 + 3) * 64 + n] = v.w;
        }
        __syncthreads();
        // ---- matvec1: t[c0+j] = relu(sum_{k<11} h[k]*W1a[k][c0+j] + ba) ----
#pragma unroll
        for (int j = 0; j < 16; ++j) acc[j] = ba[c0 + j];
#pragma unroll
        for (int k = 0; k < 11; ++k) {
            float hk = hs[k * 64 + lane];            // conflict-free
            const float* wr = W1a + k * 64 + c0;     // uniform -> s_load
#pragma unroll
            for (int j = 0; j < 16; ++j) acc[j] = fmaf(hk, wr[j], acc[j]);
        }
        __syncthreads();   // done reading hs; safe to overwrite hb
#pragma unroll
        for (int j4 = 0; j4 < 4; ++j4) {
            int q = wv * 4 + j4;
            hb4[lane * 16 + (q ^ l15)] = make_float4(
                fmaxf(acc[j4 * 4 + 0], 0.f), fmaxf(acc[j4 * 4 + 1], 0.f),
                fmaxf(acc[j4 * 4 + 2], 0.f), fmaxf(acc[j4 * 4 + 3], 0.f));
        }
        __syncthreads();
    } else {
        // ---- phase A: fp16 tile (uint4 = 8ch) -> LDS (swizzled fp32) ----
        {
            const unsigned short* aggh = (const unsigned short*)aggp;
            const uint4* a4 = (const uint4*)(aggh + (size_t)n0 * 64);
#pragma unroll
            for (int r = 0; r < 2; ++r) {
                int i = tid + r * 256;          // ushort8 index within tile
                int nt = i >> 3, q8 = i & 7;
                uint4 u = make_uint4(0, 0, 0, 0);
                if (n0 + nt < N) u = a4[i];
                float4 v0, v1;
                v0.x = h2f((unsigned short)(u.x & 0xffff));
                v0.y = h2f((unsigned short)(u.x >> 16));
                v0.z = h2f((unsigned short)(u.y & 0xffff));
                v0.w = h2f((unsigned short)(u.y >> 16));
                v1.x = h2f((unsigned short)(u.z & 0xffff));
                v1.y = h2f((unsigned short)(u.z >> 16));
                v1.z = h2f((unsigned short)(u.w & 0xffff));
                v1.w = h2f((unsigned short)(u.w >> 16));
                int sw = nt & 15;
                hb4[nt * 16 + ((2 * q8 + 0) ^ sw)] = v0;
                hb4[nt * 16 + ((2 * q8 + 1) ^ sw)] = v1;
            }
        }
        __syncthreads();
        // ---- matvec1: t[c0+j] = relu(sum_k h[k]*WaH[k][c0+j] + ba[c0+j]) ----
#pragma unroll
        for (int j = 0; j < 16; ++j) acc[j] = ba[c0 + j];
        for (int kc = 0; kc < 4; ++kc) {
            float hq[16];
#pragma unroll
            for (int q4 = 0; q4 < 4; ++q4) {
                float4 hv = hb4[lane * 16 + ((kc * 4 + q4) ^ l15)];
                hq[q4 * 4 + 0] = hv.x; hq[q4 * 4 + 1] = hv.y;
                hq[q4 * 4 + 2] = hv.z; hq[q4 * 4 + 3] = hv.w;
            }
            const unsigned short* wbase = WaH + (size_t)(kc * 16) * 64 + c0;
#pragma unroll
            for (int kk = 0; kk < 16; ++kk) {
                float w[16];
#pragma unroll
                for (int j = 0; j < 16; ++j) w[j] = h2f(wbase[kk * 64 + j]);
                float hk = hq[kk];
#pragma unroll
                for (int j = 0; j < 16; ++j) acc[j] = fmaf(hk, w[j], acc[j]);
            }
        }
        __syncthreads();   // everyone done reading h from hb
#pragma unroll
        for (int j4 = 0; j4 < 4; ++j4) {
            int q = wv * 4 + j4;
            hb4[lane * 16 + (q ^ l15)] = make_float4(
                fmaxf(acc[j4 * 4 + 0], 0.f), fmaxf(acc[j4 * 4 + 1], 0.f),
                fmaxf(acc[j4 * 4 + 2], 0.f), fmaxf(acc[j4 * 4 + 3], 0.f));
        }
        __syncthreads();
    }

    // ---- matvec2: v[c0+j] = relu(sum_k t[k]*WbH[k][c0+j] + bb[c0+j]) ----
#pragma unroll
    for (int j = 0; j < 16; ++j) acc[j] = bb[c0 + j];
    for (int kc = 0; kc < 4; ++kc) {
        float hq[16];
#pragma unroll
        for (int q4 = 0; q4 < 4; ++q4) {
            float4 hv = hb4[lane * 16 + ((kc * 4 + q4) ^ l15)];
            hq[q4 * 4 + 0] = hv.x; hq[q4 * 4 + 1] = hv.y;
            hq[q4 * 4 + 2] = hv.z; hq[q4 * 4 + 3] = hv.w;
        }
        const unsigned short* wbase = WbH + (size_t)(kc * 16) * 64 + c0;
#pragma unroll
        for (int kk = 0; kk < 16; ++kk) {
            float w[16];
#pragma unroll
            for (int j = 0; j < 16; ++j) w[j] = h2f(wbase[kk * 64 + j]);
            float hk = hq[kk];
#pragma unroll
            for (int j = 0; j < 16; ++j) acc[j] = fmaf(hk, w[j], acc[j]);
        }
    }
    __syncthreads();   // everyone done reading hb
    {
#pragma unroll
        for (int j4 = 0; j4 < 4; ++j4) {
            int q = wv * 4 + j4;
            hb4[lane * 16 + (q ^ l15)] = make_float4(
                fmaxf(acc[j4 * 4 + 0], 0.f), fmaxf(acc[j4 * 4 + 1], 0.f),
                fmaxf(acc[j4 * 4 + 2], 0.f), fmaxf(acc[j4 * 4 + 3], 0.f));
        }
    }
    __syncthreads();

    // ---- phase C: fp16 store + BN stats + graph pooling (fp32) ----
    {
        int q = lane & 15;          // channel quad
        int ng = lane >> 4;         // node subgroup
        int base_nt = wv * 16;
        float4 bs = make_float4(0, 0, 0, 0), bq = make_float4(0, 0, 0, 0);

        bool full = (n0 + base_nt + 15) < N;            // wave-uniform
        int gf = 0, gl = -1;
        if (full) { gf = batch[n0 + base_nt]; gl = batch[n0 + base_nt + 15]; }

        if (full && gf == gl) {
            // fast path: whole 16-node group in one graph
            float4 pacc = make_float4(0, 0, 0, 0);
#pragma unroll
            for (int s2 = 0; s2 < 4; ++s2) {
                int nt = base_nt + s2 * 4 + ng;
                float4 v = hb4[nt * 16 + (q ^ (nt & 15))];
                ushort4 o;
                o.x = f2h(v.x); o.y = f2h(v.y); o.z = f2h(v.z); o.w = f2h(v.w);
                *(ushort4*)(vout + (size_t)(n0 + nt) * 64 + q * 4) = o;
                bs.x += v.x; bs.y += v.y; bs.z += v.z; bs.w += v.w;
                bq.x += v.x * v.x; bq.y += v.y * v.y;
                bq.z += v.z * v.z; bq.w += v.w * v.w;
                pacc.x += v.x; pacc.y += v.y; pacc.z += v.z; pacc.w += v.w;
            }
#pragma unroll
            for (int off = 16; off < 64; off <<= 1) {
                pacc.x += __shfl_xor(pacc.x, off); pacc.y += __shfl_xor(pacc.y, off);
                pacc.z += __shfl_xor(pacc.z, off); pacc.w += __shfl_xor(pacc.w, off);
            }
            if (ng == 0) {
                atomicAdd(&Sg[gf * 64 + q * 4 + 0], pacc.x);
                atomicAdd(&Sg[gf * 64 + q * 4 + 1], pacc.y);
                atomicAdd(&Sg[gf * 64 + q * 4 + 2], pacc.z);
                atomicAdd(&Sg[gf * 64 + q * 4 + 3], pacc.w);
            }
        } else {
            // slow path: graph boundary inside the group (or tile tail)
            float4 pacc = make_float4(0, 0, 0, 0);
            int curg = -1;
#pragma unroll
            for (int s2 = 0; s2 < 4; ++s2) {
                int nt = base_nt + s2 * 4 + ng;
                int n = n0 + nt;
                if (n < N) {
                    float4 v = hb4[nt * 16 + (q ^ (nt & 15))];
                    ushort4 o;
                    o.x = f2h(v.x); o.y = f2h(v.y); o.z = f2h(v.z); o.w = f2h(v.w);
                    *(ushort4*)(vout + (size_t)n * 64 + q * 4) = o;
                    bs.x += v.x; bs.y += v.y; bs.z += v.z; bs.w += v.w;
                    bq.x += v.x * v.x; bq.y += v.y * v.y;
                    bq.z += v.z * v.z; bq.w += v.w * v.w;
                    int g = batch[n];
                    if (g != curg) {
                        if (curg >= 0) {
                            atomicAdd(&Sg[curg * 64 + q * 4 + 0], pacc.x);
                            atomicAdd(&Sg[curg * 64 + q * 4 + 1], pacc.y);
                            atomicAdd(&Sg[curg * 64 + q * 4 + 2], pacc.z);
                            atomicAdd(&Sg[curg * 64 + q * 4 + 3], pacc.w);
                        }
                        curg = g;
                        pacc = make_float4(0, 0, 0, 0);
                    }
                    pacc.x += v.x; pacc.y += v.y; pacc.z += v.z; pacc.w += v.w;
                }
            }
            if (curg >= 0) {
                atomicAdd(&Sg[curg * 64 + q * 4 + 0], pacc.x);
                atomicAdd(&Sg[curg * 64 + q * 4 + 1], pacc.y);
                atomicAdd(&Sg[curg * 64 + q * 4 + 2], pacc.z);
                atomicAdd(&Sg[curg * 64 + q * 4 + 3], pacc.w);
            }
        }
#pragma unroll
        for (int off = 16; off < 64; off <<= 1) {
            bs.x += __shfl_xor(bs.x, off); bs.y += __shfl_xor(bs.y, off);
            bs.z += __shfl_xor(bs.z, off); bs.w += __shfl_xor(bs.w, off);
            bq.x += __shfl_xor(bq.x, off); bq.y += __shfl_xor(bq.y, off);
            bq.z += __shfl_xor(bq.z, off); bq.w += __shfl_xor(bq.w, off);
        }
        if (ng == 0) {
            float* bkt = bnpart + (blockIdx.x & 31) * 128;
            atomicAdd(&bkt[q * 4 + 0], bs.x);
            atomicAdd(&bkt[q * 4 + 1], bs.y);
            atomicAdd(&bkt[q * 4 + 2], bs.z);
            atomicAdd(&bkt[q * 4 + 3], bs.w);
            atomicAdd(&bkt[64 + q * 4 + 0], bq.x);
            atomicAdd(&bkt[64 + q * 4 + 1], bq.y);
            atomicAdd(&bkt[64 + q * 4 + 2], bq.z);
            atomicAdd(&bkt[64 + q * 4 + 3], bq.w);
        }
    }
}

__global__ void k_bnstat(const float* __restrict__ bnpart,
        const float* __restrict__ gamma, const float* __restrict__ beta,
        float* __restrict__ a, float* __restrict__ b, int N) {
    int c = threadIdx.x;  // 64 threads
    float s = 0.f, q = 0.f;
    for (int i = 0; i < 32; ++i) { s += bnpart[i * 128 + c]; q += bnpart[i * 128 + 64 + c]; }
    float invN = 1.0f / (float)N;
    float mu = s * invN;
    float var = q * invN - mu * mu;
    float ac = gamma[c] * rsqrtf(var + 1e-5f);
    a[c] = ac;
    b[c] = beta[c] - mu * ac;
}

// Head: z[g,320] = concat_l (a_l*S_l[g] + b_l*cnt[g]); out = relu(z@fc1+b)@fc2+b
__global__ __launch_bounds__(256) void k_final(
        const float* __restrict__ S, const float* __restrict__ ab,
        const int* __restrict__ cntg,
        const float* __restrict__ fc1W, const float* __restrict__ fc1b,
        const float* __restrict__ fc2W, const float* __restrict__ fc2b,
        float* __restrict__ out, int G) {
    __shared__ float zbuf[4][320];
    int tid = threadIdx.x;
    int lane = tid & 63, wv = tid >> 6;
    int g = blockIdx.x * 4 + wv;
    if (g >= G) return;
    float cf = (float)cntg[g];
#pragma unroll
    for (int l = 0; l < 5; ++l) {
        float a = ab[l * 128 + lane];
        float b = ab[l * 128 + 64 + lane];
        zbuf[wv][l * 64 + lane] = a * S[((size_t)l * G + g) * 64 + lane] + b * cf;
    }
    float acc = fc1b[lane];
    for (int k = 0; k < 320; ++k) acc += zbuf[wv][k] * fc1W[k * 64 + lane];
    float t = fmaxf(acc, 0.f);
    float r = t * fc2W[lane];
#pragma unroll
    for (int off = 32; off >= 1; off >>= 1) r += __shfl_xor(r, off);
    if (lane == 0) out[g] = r + fc2b[0];
}

extern "C" void kernel_launch(void* const* d_in, const int* in_sizes, int n_in,
                              void* d_out, int out_size, void* d_ws, size_t ws_size,
                              hipStream_t stream) {
    const float* x    = (const float*)d_in[0];
    const int*   ei   = (const int*)d_in[1];
    const int*   batch= (const int*)d_in[2];
    const float* W1a  = (const float*)d_in[3];
    const float* b1a  = (const float*)d_in[4];
    const float* W1b  = (const float*)d_in[5];
    const float* b1b  = (const float*)d_in[6];
    const float* Wa   = (const float*)d_in[7];
    const float* ba   = (const float*)d_in[8];
    const float* Wb   = (const float*)d_in[9];
    const float* bb   = (const float*)d_in[10];
    const float* gamma= (const float*)d_in[11];
    const float* beta = (const float*)d_in[12];
    const float* fc1W = (const float*)d_in[13];
    const float* fc1b = (const float*)d_in[14];
    const float* fc2W = (const float*)d_in[15];
    const float* fc2b = (const float*)d_in[16];

    const int N = in_sizes[2];
    const int E = in_sizes[1] / 2;
    const int G = out_size;
    const int* srcp = ei;
    const int* dstp = ei + E;

    char* p = (char*)d_ws;
    auto alloc = [&](size_t bytes) {
        char* r = p;
        p += (bytes + 255) & ~size_t(255);
        return r;
    };
    unsigned short* aggh = (unsigned short*)alloc((size_t)N * 64 * 2);
    unsigned short* vb   = (unsigned short*)alloc((size_t)N * 64 * 2);
    int*   col    = (int*)  alloc((size_t)E * 4);
    int*   rank_  = (int*)  alloc((size_t)E * 4);
    int*   rp     = (int*)  alloc((size_t)(N + 1) * 4);
    unsigned short* x16h = (unsigned short*)alloc((size_t)N * 16 * 2);
    float* h16    = (float*)alloc((size_t)N * 16 * 4);
    unsigned short* W1bH = (unsigned short*)alloc(4096 * 2);
    unsigned short* WaH  = (unsigned short*)alloc((size_t)4 * 4096 * 2);
    unsigned short* WbH  = (unsigned short*)alloc((size_t)4 * 4096 * 2);
    int*   bsum   = (int*)  alloc(512);
    int*   boffs  = (int*)  alloc(512);
    float* ab     = (float*)alloc(5 * 128 * 4);
    // ---- zeroed region (single memset) ----
    char*  z0     = p;
    int*   cntn   = (int*)  alloc((size_t)N * 4);
    int*   cntg   = (int*)  alloc((size_t)G * 4);
    float* S      = (float*)alloc((size_t)5 * G * 64 * 4);
    float* bnpart = (float*)alloc((size_t)5 * 32 * 128 * 4);
    size_t zbytes = (size_t)(p - z0);

    hipMemsetAsync(z0, 0, zbytes, stream);

    int nb_e = (E + 255) / 256;
    int nb_n = (N + 255) / 256;
    int nb_scan = (N + SCAN_ELEMS - 1) / SCAN_ELEMS;
    k_hist<<<nb_e, 256, 0, stream>>>(dstp, E, cntn, rank_);
    k_prep<<<nb_n, 256, 0, stream>>>(x, x16h, batch, cntg, N,
        W1b, Wa, Wb, W1bH, WaH, WbH);
    k_scan1<<<nb_scan, 256, 0, stream>>>(cntn, N, rp, bsum);
    k_scan2<<<1, 128, 0, stream>>>(bsum, nb_scan, boffs);
    k_scan3<<<(N + 255) / 256, 256, 0, stream>>>(rp, N, boffs, E);
    k_fill<<<nb_e, 256, 0, stream>>>(srcp, dstp, rank_, E, rp, col);

    int nb_node = (N + 3) / 4;
    int nb_tile = (N + 63) / 64;

    // Layer 1: 16-dim fp16 gather, then mlp<FIRST> does W1a from h16 (fp32)
    k_gather16<<<nb_node, 256, 0, stream>>>(x16h, h16, rp, col, N);
    k_mlp<true><<<nb_tile, 256, 0, stream>>>(h16, vb, batch,
        W1a, nullptr, b1a, W1bH, b1b, S, bnpart, N);
    k_bnstat<<<1, 64, 0, stream>>>(bnpart, gamma, beta, ab, ab + 64, N);

    for (int l = 0; l < 4; ++l) {
        k_gather<<<nb_node, 256, 0, stream>>>(vb, aggh, rp, col,
            ab + l * 128, N);
        k_mlp<false><<<nb_tile, 256, 0, stream>>>(aggh, vb, batch,
            nullptr, WaH + (size_t)l * 4096, ba + l * 64,
            WbH + (size_t)l * 4096, bb + l * 64,
            S + (size_t)(l + 1) * G * 64,
            bnpart + (size_t)(l + 1) * 32 * 128, N);
        k_bnstat<<<1, 64, 0, stream>>>(
            bnpart + (size_t)(l + 1) * 32 * 128,
            gamma + (l + 1) * 64, beta + (l + 1) * 64,
            ab + (l + 1) * 128, ab + (l + 1) * 128 + 64, N);
    }

    k_final<<<(G + 3) / 4, 256, 0, stream>>>(S, ab, cntg, fc1W, fc1b, fc2W, fc2b,
                                             (float*)d_out, G);
}

// Round 15
// 760.342 us; speedup vs baseline: 1.3041x; 1.2883x over previous
//
#include <hip/hip_runtime.h>
#include <hip/hip_fp16.h>

// ---------------------------------------------------------------------------
// GIN (5 layers) + BN + graph pooling + MLP head.
// R15: exact revert to R12 (measured best: 762us, absmax 0.0625).
//      R13 (MFMA mlp) and R14 (fp16 weights) both regressed k_mlp:
//      R13 built a thin latency chain (MfmaUtil 0.5%, occ 31%); R14 fell off
//      the scalar pipe (SGPR 112->48: SMEM is dword-granular, ushort loads
//      became per-lane vector broadcasts + 1024 v_cvt/matvec).
//      Component floors (measured): k_hist 67us = 56MB atomic write-through;
//      k_fill ~55us = scatter line ping-pong; gathers = fp16 + 16-deep ILP
//      at L2/L3 floor; k_mlp = VALU/s_load balanced (two attacks regressed).
// ---------------------------------------------------------------------------

#define SCAN_ELEMS 1024

__device__ __forceinline__ unsigned short f2h(float f) {
    return __half_as_ushort(__float2half_rn(f));
}
__device__ __forceinline__ float h2f(unsigned short s) {
    return __half2float(__ushort_as_half(s));
}

// Edge-only histogram + rank (atomic returns slot)
__global__ __launch_bounds__(256) void k_hist(const int* __restrict__ dst, int E,
        int* __restrict__ cnt_node, int* __restrict__ rank_) {
    int i = blockIdx.x * blockDim.x + threadIdx.x;
    if (i < E) rank_[i] = atomicAdd(&cnt_node[dst[i]], 1);
}

// Node prep: x -> fp16 padded 16ch, graph counts
__global__ __launch_bounds__(256) void k_prep(const float* __restrict__ x,
        unsigned short* __restrict__ x16h, const int* __restrict__ batch,
        int* __restrict__ cnt_graph, int N) {
    int i = blockIdx.x * blockDim.x + threadIdx.x;
    if (i < N) {
        atomicAdd(&cnt_graph[batch[i]], 1);
#pragma unroll
        for (int k = 0; k < 11; ++k) x16h[i * 16 + k] = f2h(x[i * 11 + k]);
#pragma unroll
        for (int k = 11; k < 16; ++k) x16h[i * 16 + k] = 0;
    }
}

__global__ __launch_bounds__(256) void k_scan1(const int* __restrict__ cnt, int n,
        int* __restrict__ rp, int* __restrict__ bsum) {
    __shared__ int sdata[256];
    int t = threadIdx.x;
    int base = blockIdx.x * SCAN_ELEMS + t * 4;
    int v0 = (base + 0 < n) ? cnt[base + 0] : 0;
    int v1 = (base + 1 < n) ? cnt[base + 1] : 0;
    int v2 = (base + 2 < n) ? cnt[base + 2] : 0;
    int v3 = (base + 3 < n) ? cnt[base + 3] : 0;
    int tsum = v0 + v1 + v2 + v3;
    sdata[t] = tsum;
    __syncthreads();
    for (int off = 1; off < 256; off <<= 1) {
        int val = (t >= off) ? sdata[t - off] : 0;
        __syncthreads();
        sdata[t] += val;
        __syncthreads();
    }
    int excl = sdata[t] - tsum;
    if (t == 255) bsum[blockIdx.x] = sdata[255];
    if (base + 0 < n) rp[base + 0] = excl;
    if (base + 1 < n) rp[base + 1] = excl + v0;
    if (base + 2 < n) rp[base + 2] = excl + v0 + v1;
    if (base + 3 < n) rp[base + 3] = excl + v0 + v1 + v2;
}

__global__ __launch_bounds__(128) void k_scan2(const int* __restrict__ bsum, int nb,
        int* __restrict__ boffs) {
    __shared__ int sd[128];
    int t = threadIdx.x;
    int v = (t < nb) ? bsum[t] : 0;
    sd[t] = v;
    __syncthreads();
    for (int off = 1; off < 128; off <<= 1) {
        int val = (t >= off) ? sd[t - off] : 0;
        __syncthreads();
        sd[t] += val;
        __syncthreads();
    }
    if (t < nb) boffs[t] = sd[t] - v;
}

__global__ __launch_bounds__(256) void k_scan3(int* __restrict__ rp, int n,
        const int* __restrict__ boffs, int E) {
    int i = blockIdx.x * blockDim.x + threadIdx.x;
    if (i < n) rp[i] += boffs[i / SCAN_ELEMS];
    if (i == 0) rp[n] = E;
}

__global__ __launch_bounds__(256) void k_fill(const int* __restrict__ src,
        const int* __restrict__ dst, const int* __restrict__ rank_, int E,
        const int* __restrict__ rp, int* __restrict__ col) {
    int e = blockIdx.x * blockDim.x + threadIdx.x;
    if (e < E) {
        __builtin_nontemporal_store(src[e], &col[rp[dst[e]] + rank_[e]]);
    }
}

// Layer-1 gather in padded 11->16 dim fp16 space: wave = 1 node, 4 edges per
// step (16 lanes per edge), 4-deep -> 16 edges in flight. fp32 out.
__global__ __launch_bounds__(256, 8) void k_gather16(
        const unsigned short* __restrict__ x16h, float* __restrict__ h16,
        const int* __restrict__ rp, const int* __restrict__ col, int N) {
    int lane = threadIdx.x & 63, wv = threadIdx.x >> 6;
    int n = blockIdx.x * 4 + wv;
    if (n >= N) return;
    int sub = lane >> 4, c = lane & 15;
    int start = rp[n], end = rp[n + 1];
    float s0 = 0.f, s1 = 0.f, s2 = 0.f, s3 = 0.f;
    int eb = start;
    for (; eb + 16 <= end; eb += 16) {
        int j0 = col[eb + sub];
        int j1 = col[eb + 4 + sub];
        int j2 = col[eb + 8 + sub];
        int j3 = col[eb + 12 + sub];
        s0 += h2f(x16h[(size_t)j0 * 16 + c]);
        s1 += h2f(x16h[(size_t)j1 * 16 + c]);
        s2 += h2f(x16h[(size_t)j2 * 16 + c]);
        s3 += h2f(x16h[(size_t)j3 * 16 + c]);
    }
    for (; eb + 4 <= end; eb += 4) {
        int j0 = col[eb + sub];
        s0 += h2f(x16h[(size_t)j0 * 16 + c]);
    }
    for (int e = eb + sub; e < end; e += 4) {
        s1 += h2f(x16h[(size_t)col[e] * 16 + c]);
    }
    float s = (s0 + s1) + (s2 + s3);
    s += __shfl_xor(s, 16);
    s += __shfl_xor(s, 32);
    if (lane < 16) {
        h16[(size_t)n * 16 + lane] = s + h2f(x16h[(size_t)n * 16 + lane]);
    }
}

// Gather (layers 2-5): one wave per node, lane = channel, fp16 in/out.
// s = v_n + sum_j v_j; h2 = a*s + b*(1+deg) in fp32; 16-deep load ILP.
__global__ __launch_bounds__(256, 8) void k_gather(
        const unsigned short* __restrict__ vin, unsigned short* __restrict__ aggh,
        const int* __restrict__ rp, const int* __restrict__ col,
        const float* __restrict__ ab_prev, int N) {
    int lane = threadIdx.x & 63, wv = threadIdx.x >> 6;
    int n = blockIdx.x * 4 + wv;
    if (n >= N) return;
    float a = ab_prev[lane];
    float b = ab_prev[64 + lane];
    int start = rp[n], end = rp[n + 1];
    float s[16];
#pragma unroll
    for (int u = 0; u < 16; ++u) s[u] = 0.f;
    s[0] = h2f(vin[(size_t)n * 64 + lane]);
    int e = start;
    for (; e + 16 <= end; e += 16) {
        int j[16];
#pragma unroll
        for (int u = 0; u < 16; ++u) j[u] = col[e + u];
#pragma unroll
        for (int u = 0; u < 16; ++u)
            s[u] += h2f(vin[(size_t)j[u] * 64 + lane]);
    }
    for (; e + 4 <= end; e += 4) {
        int j0 = col[e + 0], j1 = col[e + 1], j2 = col[e + 2], j3 = col[e + 3];
        s[0] += h2f(vin[(size_t)j0 * 64 + lane]);
        s[1] += h2f(vin[(size_t)j1 * 64 + lane]);
        s[2] += h2f(vin[(size_t)j2 * 64 + lane]);
        s[3] += h2f(vin[(size_t)j3 * 64 + lane]);
    }
    for (; e < end; ++e) s[0] += h2f(vin[(size_t)col[e] * 64 + lane]);
#pragma unroll
    for (int u = 8; u > 0; u >>= 1)
#pragma unroll
        for (int v2 = 0; v2 < u; ++v2) s[v2] += s[v2 + u];
    float h2 = fmaf(a, s[0], b * (float)(1 + end - start));
    aggh[(size_t)n * 64 + lane] = f2h(h2);
}

// MLP: one block = one 64-node tile. k-chunked matvecs; weights fp32 via the
// scalar pipe (readfirstlane-uniform addresses -> s_load). fp16 in/out.
template <bool FIRST>
__global__ __launch_bounds__(256, 4) void k_mlp(
        const void* __restrict__ aggp, unsigned short* __restrict__ vout,
        const int* __restrict__ batch,
        const float* __restrict__ Wa, const float* __restrict__ ba,
        const float* __restrict__ Wb, const float* __restrict__ bb,
        float* __restrict__ Sg, float* __restrict__ bnpart,
        int N) {
    __shared__ float hb[64 * 64];
    float4* hb4 = (float4*)hb;
    const int tid = threadIdx.x;
    const int lane = tid & 63;
    const int wv = tid >> 6;
    const int n0 = blockIdx.x * 64;
    const int l15 = lane & 15;
    // wave-uniform channel base, provably uniform -> weight reads use s_load
    const int c0 = __builtin_amdgcn_readfirstlane(wv) * 16;

    float acc[16];

    if (FIRST) {
        // ---- phase A': h16 (fp32 Nx16) -> transposed LDS hs[k][node] ----
        const float* h16 = (const float*)aggp;
        float* hs = hb;
        {
            int n = tid >> 2, kq = tid & 3;
            float4 v = make_float4(0.f, 0.f, 0.f, 0.f);
            if (n0 + n < N) v = ((const float4*)h16)[(size_t)n0 * 4 + tid];
            hs[(kq * 4 + 0) * 64 + n] = v.x;
            hs[(kq * 4 + 1) * 64 + n] = v.y;
            hs[(kq * 4 + 2) * 64 + n] = v.z;
            hs[(kq * 4 + 3) * 64 + n] = v.w;
        }
        __syncthreads();
        // ---- matvec1: t[c0+j] = relu(sum_{k<11} h[k]*W1a[k][c0+j] + ba) ----
#pragma unroll
        for (int j = 0; j < 16; ++j) acc[j] = ba[c0 + j];
#pragma unroll
        for (int k = 0; k < 11; ++k) {
            float hk = hs[k * 64 + lane];            // conflict-free
            const float* wr = Wa + k * 64 + c0;      // uniform -> s_load
#pragma unroll
            for (int j = 0; j < 16; ++j) acc[j] = fmaf(hk, wr[j], acc[j]);
        }
        __syncthreads();   // done reading hs; safe to overwrite hb
#pragma unroll
        for (int j4 = 0; j4 < 4; ++j4) {
            int q = wv * 4 + j4;
            hb4[lane * 16 + (q ^ l15)] = make_float4(
                fmaxf(acc[j4 * 4 + 0], 0.f), fmaxf(acc[j4 * 4 + 1], 0.f),
                fmaxf(acc[j4 * 4 + 2], 0.f), fmaxf(acc[j4 * 4 + 3], 0.f));
        }
        __syncthreads();
    } else {
        // ---- phase A: fp16 tile (uint4 = 8ch) -> LDS (swizzled fp32) ----
        {
            const unsigned short* aggh = (const unsigned short*)aggp;
            const uint4* a4 = (const uint4*)(aggh + (size_t)n0 * 64);
#pragma unroll
            for (int r = 0; r < 2; ++r) {
                int i = tid + r * 256;          // ushort8 index within tile
                int nt = i >> 3, q8 = i & 7;
                uint4 u = make_uint4(0, 0, 0, 0);
                if (n0 + nt < N) u = a4[i];
                float4 v0, v1;
                v0.x = h2f((unsigned short)(u.x & 0xffff));
                v0.y = h2f((unsigned short)(u.x >> 16));
                v0.z = h2f((unsigned short)(u.y & 0xffff));
                v0.w = h2f((unsigned short)(u.y >> 16));
                v1.x = h2f((unsigned short)(u.z & 0xffff));
                v1.y = h2f((unsigned short)(u.z >> 16));
                v1.z = h2f((unsigned short)(u.w & 0xffff));
                v1.w = h2f((unsigned short)(u.w >> 16));
                int sw = nt & 15;
                hb4[nt * 16 + ((2 * q8 + 0) ^ sw)] = v0;
                hb4[nt * 16 + ((2 * q8 + 1) ^ sw)] = v1;
            }
        }
        __syncthreads();
        // ---- matvec1: t[c0+j] = relu(sum_k h[k]*Wa[k][c0+j] + ba[c0+j]) ----
#pragma unroll
        for (int j = 0; j < 16; ++j) acc[j] = ba[c0 + j];
        for (int kc = 0; kc < 4; ++kc) {
            float hq[16];
#pragma unroll
            for (int q4 = 0; q4 < 4; ++q4) {
                float4 hv = hb4[lane * 16 + ((kc * 4 + q4) ^ l15)];
                hq[q4 * 4 + 0] = hv.x; hq[q4 * 4 + 1] = hv.y;
                hq[q4 * 4 + 2] = hv.z; hq[q4 * 4 + 3] = hv.w;
            }
            const float* wbase = Wa + (size_t)(kc * 16) * 64 + c0;   // uniform
#pragma unroll
            for (int kk = 0; kk < 16; ++kk) {
                float w[16];
#pragma unroll
                for (int j = 0; j < 16; ++j) w[j] = wbase[kk * 64 + j];  // s_load
                float hk = hq[kk];
#pragma unroll
                for (int j = 0; j < 16; ++j) acc[j] = fmaf(hk, w[j], acc[j]);
            }
        }
        __syncthreads();   // everyone done reading h from hb
#pragma unroll
        for (int j4 = 0; j4 < 4; ++j4) {
            int q = wv * 4 + j4;
            hb4[lane * 16 + (q ^ l15)] = make_float4(
                fmaxf(acc[j4 * 4 + 0], 0.f), fmaxf(acc[j4 * 4 + 1], 0.f),
                fmaxf(acc[j4 * 4 + 2], 0.f), fmaxf(acc[j4 * 4 + 3], 0.f));
        }
        __syncthreads();
    }

    // ---- matvec2: v[c0+j] = relu(sum_k t[k]*Wb[k][c0+j] + bb[c0+j]) ----
#pragma unroll
    for (int j = 0; j < 16; ++j) acc[j] = bb[c0 + j];
    for (int kc = 0; kc < 4; ++kc) {
        float hq[16];
#pragma unroll
        for (int q4 = 0; q4 < 4; ++q4) {
            float4 hv = hb4[lane * 16 + ((kc * 4 + q4) ^ l15)];
            hq[q4 * 4 + 0] = hv.x; hq[q4 * 4 + 1] = hv.y;
            hq[q4 * 4 + 2] = hv.z; hq[q4 * 4 + 3] = hv.w;
        }
        const float* wbase = Wb + (size_t)(kc * 16) * 64 + c0;       // uniform
#pragma unroll
        for (int kk = 0; kk < 16; ++kk) {
            float w[16];
#pragma unroll
            for (int j = 0; j < 16; ++j) w[j] = wbase[kk * 64 + j];  // s_load
            float hk = hq[kk];
#pragma unroll
            for (int j = 0; j < 16; ++j) acc[j] = fmaf(hk, w[j], acc[j]);
        }
    }
    __syncthreads();   // everyone done reading hb
    {
#pragma unroll
        for (int j4 = 0; j4 < 4; ++j4) {
            int q = wv * 4 + j4;
            hb4[lane * 16 + (q ^ l15)] = make_float4(
                fmaxf(acc[j4 * 4 + 0], 0.f), fmaxf(acc[j4 * 4 + 1], 0.f),
                fmaxf(acc[j4 * 4 + 2], 0.f), fmaxf(acc[j4 * 4 + 3], 0.f));
        }
    }
    __syncthreads();

    // ---- phase C: fp16 store + BN stats + graph pooling (fp32) ----
    {
        int q = lane & 15;          // channel quad
        int ng = lane >> 4;         // node subgroup
        int base_nt = wv * 16;
        float4 bs = make_float4(0, 0, 0, 0), bq = make_float4(0, 0, 0, 0);

        bool full = (n0 + base_nt + 15) < N;            // wave-uniform
        int gf = 0, gl = -1;
        if (full) { gf = batch[n0 + base_nt]; gl = batch[n0 + base_nt + 15]; }

        if (full && gf == gl) {
            // fast path: whole 16-node group in one graph
            float4 pacc = make_float4(0, 0, 0, 0);
#pragma unroll
            for (int s2 = 0; s2 < 4; ++s2) {
                int nt = base_nt + s2 * 4 + ng;
                float4 v = hb4[nt * 16 + (q ^ (nt & 15))];
                ushort4 o;
                o.x = f2h(v.x); o.y = f2h(v.y); o.z = f2h(v.z); o.w = f2h(v.w);
                *(ushort4*)(vout + (size_t)(n0 + nt) * 64 + q * 4) = o;
                bs.x += v.x; bs.y += v.y; bs.z += v.z; bs.w += v.w;
                bq.x += v.x * v.x; bq.y += v.y * v.y;
                bq.z += v.z * v.z; bq.w += v.w * v.w;
                pacc.x += v.x; pacc.y += v.y; pacc.z += v.z; pacc.w += v.w;
            }
#pragma unroll
            for (int off = 16; off < 64; off <<= 1) {
                pacc.x += __shfl_xor(pacc.x, off); pacc.y += __shfl_xor(pacc.y, off);
                pacc.z += __shfl_xor(pacc.z, off); pacc.w += __shfl_xor(pacc.w, off);
            }
            if (ng == 0) {
                atomicAdd(&Sg[gf * 64 + q * 4 + 0], pacc.x);
                atomicAdd(&Sg[gf * 64 + q * 4 + 1], pacc.y);
                atomicAdd(&Sg[gf * 64 + q * 4 + 2], pacc.z);
                atomicAdd(&Sg[gf * 64 + q * 4 + 3], pacc.w);
            }
        } else {
            // slow path: graph boundary inside the group (or tile tail)
            float4 pacc = make_float4(0, 0, 0, 0);
            int curg = -1;
#pragma unroll
            for (int s2 = 0; s2 < 4; ++s2) {
                int nt = base_nt + s2 * 4 + ng;
                int n = n0 + nt;
                if (n < N) {
                    float4 v = hb4[nt * 16 + (q ^ (nt & 15))];
                    ushort4 o;
                    o.x = f2h(v.x); o.y = f2h(v.y); o.z = f2h(v.z); o.w = f2h(v.w);
                    *(ushort4*)(vout + (size_t)n * 64 + q * 4) = o;
                    bs.x += v.x; bs.y += v.y; bs.z += v.z; bs.w += v.w;
                    bq.x += v.x * v.x; bq.y += v.y * v.y;
                    bq.z += v.z * v.z; bq.w += v.w * v.w;
                    int g = batch[n];
                    if (g != curg) {
                        if (curg >= 0) {
                            atomicAdd(&Sg[curg * 64 + q * 4 + 0], pacc.x);
                            atomicAdd(&Sg[curg * 64 + q * 4 + 1], pacc.y);
                            atomicAdd(&Sg[curg * 64 + q * 4 + 2], pacc.z);
                            atomicAdd(&Sg[curg * 64 + q * 4 + 3], pacc.w);
                        }
                        curg = g;
                        pacc = make_float4(0, 0, 0, 0);
                    }
                    pacc.x += v.x; pacc.y += v.y; pacc.z += v.z; pacc.w += v.w;
                }
            }
            if (curg >= 0) {
                atomicAdd(&Sg[curg * 64 + q * 4 + 0], pacc.x);
                atomicAdd(&Sg[curg * 64 + q * 4 + 1], pacc.y);
                atomicAdd(&Sg[curg * 64 + q * 4 + 2], pacc.z);
                atomicAdd(&Sg[curg * 64 + q * 4 + 3], pacc.w);
            }
        }
#pragma unroll
        for (int off = 16; off < 64; off <<= 1) {
            bs.x += __shfl_xor(bs.x, off); bs.y += __shfl_xor(bs.y, off);
            bs.z += __shfl_xor(bs.z, off); bs.w += __shfl_xor(bs.w, off);
            bq.x += __shfl_xor(bq.x, off); bq.y += __shfl_xor(bq.y, off);
            bq.z += __shfl_xor(bq.z, off); bq.w += __shfl_xor(bq.w, off);
        }
        if (ng == 0) {
            float* bkt = bnpart + (blockIdx.x & 31) * 128;
            atomicAdd(&bkt[q * 4 + 0], bs.x);
            atomicAdd(&bkt[q * 4 + 1], bs.y);
            atomicAdd(&bkt[q * 4 + 2], bs.z);
            atomicAdd(&bkt[q * 4 + 3], bs.w);
            atomicAdd(&bkt[64 + q * 4 + 0], bq.x);
            atomicAdd(&bkt[64 + q * 4 + 1], bq.y);
            atomicAdd(&bkt[64 + q * 4 + 2], bq.z);
            atomicAdd(&bkt[64 + q * 4 + 3], bq.w);
        }
    }
}

__global__ void k_bnstat(const float* __restrict__ bnpart,
        const float* __restrict__ gamma, const float* __restrict__ beta,
        float* __restrict__ a, float* __restrict__ b, int N) {
    int c = threadIdx.x;  // 64 threads
    float s = 0.f, q = 0.f;
    for (int i = 0; i < 32; ++i) { s += bnpart[i * 128 + c]; q += bnpart[i * 128 + 64 + c]; }
    float invN = 1.0f / (float)N;
    float mu = s * invN;
    float var = q * invN - mu * mu;
    float ac = gamma[c] * rsqrtf(var + 1e-5f);
    a[c] = ac;
    b[c] = beta[c] - mu * ac;
}

// Head: z[g,320] = concat_l (a_l*S_l[g] + b_l*cnt[g]); out = relu(z@fc1+b)@fc2+b
__global__ __launch_bounds__(256) void k_final(
        const float* __restrict__ S, const float* __restrict__ ab,
        const int* __restrict__ cntg,
        const float* __restrict__ fc1W, const float* __restrict__ fc1b,
        const float* __restrict__ fc2W, const float* __restrict__ fc2b,
        float* __restrict__ out, int G) {
    __shared__ float zbuf[4][320];
    int tid = threadIdx.x;
    int lane = tid & 63, wv = tid >> 6;
    int g = blockIdx.x * 4 + wv;
    if (g >= G) return;
    float cf = (float)cntg[g];
#pragma unroll
    for (int l = 0; l < 5; ++l) {
        float a = ab[l * 128 + lane];
        float b = ab[l * 128 + 64 + lane];
        zbuf[wv][l * 64 + lane] = a * S[((size_t)l * G + g) * 64 + lane] + b * cf;
    }
    float acc = fc1b[lane];
    for (int k = 0; k < 320; ++k) acc += zbuf[wv][k] * fc1W[k * 64 + lane];
    float t = fmaxf(acc, 0.f);
    float r = t * fc2W[lane];
#pragma unroll
    for (int off = 32; off >= 1; off >>= 1) r += __shfl_xor(r, off);
    if (lane == 0) out[g] = r + fc2b[0];
}

extern "C" void kernel_launch(void* const* d_in, const int* in_sizes, int n_in,
                              void* d_out, int out_size, void* d_ws, size_t ws_size,
                              hipStream_t stream) {
    const float* x    = (const float*)d_in[0];
    const int*   ei   = (const int*)d_in[1];
    const int*   batch= (const int*)d_in[2];
    const float* W1a  = (const float*)d_in[3];
    const float* b1a  = (const float*)d_in[4];
    const float* W1b  = (const float*)d_in[5];
    const float* b1b  = (const float*)d_in[6];
    const float* Wa   = (const float*)d_in[7];
    const float* ba   = (const float*)d_in[8];
    const float* Wb   = (const float*)d_in[9];
    const float* bb   = (const float*)d_in[10];
    const float* gamma= (const float*)d_in[11];
    const float* beta = (const float*)d_in[12];
    const float* fc1W = (const float*)d_in[13];
    const float* fc1b = (const float*)d_in[14];
    const float* fc2W = (const float*)d_in[15];
    const float* fc2b = (const float*)d_in[16];

    const int N = in_sizes[2];
    const int E = in_sizes[1] / 2;
    const int G = out_size;
    const int* srcp = ei;
    const int* dstp = ei + E;

    char* p = (char*)d_ws;
    auto alloc = [&](size_t bytes) {
        char* r = p;
        p += (bytes + 255) & ~size_t(255);
        return r;
    };
    unsigned short* aggh = (unsigned short*)alloc((size_t)N * 64 * 2);
    unsigned short* vb   = (unsigned short*)alloc((size_t)N * 64 * 2);
    int*   col    = (int*)  alloc((size_t)E * 4);
    int*   rank_  = (int*)  alloc((size_t)E * 4);
    int*   rp     = (int*)  alloc((size_t)(N + 1) * 4);
    unsigned short* x16h = (unsigned short*)alloc((size_t)N * 16 * 2);
    float* h16    = (float*)alloc((size_t)N * 16 * 4);
    int*   bsum   = (int*)  alloc(512);
    int*   boffs  = (int*)  alloc(512);
    float* ab     = (float*)alloc(5 * 128 * 4);
    // ---- zeroed region (single memset) ----
    char*  z0     = p;
    int*   cntn   = (int*)  alloc((size_t)N * 4);
    int*   cntg   = (int*)  alloc((size_t)G * 4);
    float* S      = (float*)alloc((size_t)5 * G * 64 * 4);
    float* bnpart = (float*)alloc((size_t)5 * 32 * 128 * 4);
    size_t zbytes = (size_t)(p - z0);

    hipMemsetAsync(z0, 0, zbytes, stream);

    int nb_e = (E + 255) / 256;
    int nb_n = (N + 255) / 256;
    int nb_scan = (N + SCAN_ELEMS - 1) / SCAN_ELEMS;
    k_hist<<<nb_e, 256, 0, stream>>>(dstp, E, cntn, rank_);
    k_prep<<<nb_n, 256, 0, stream>>>(x, x16h, batch, cntg, N);
    k_scan1<<<nb_scan, 256, 0, stream>>>(cntn, N, rp, bsum);
    k_scan2<<<1, 128, 0, stream>>>(bsum, nb_scan, boffs);
    k_scan3<<<(N + 255) / 256, 256, 0, stream>>>(rp, N, boffs, E);
    k_fill<<<nb_e, 256, 0, stream>>>(srcp, dstp, rank_, E, rp, col);

    int nb_node = (N + 3) / 4;
    int nb_tile = (N + 63) / 64;

    // Layer 1: 16-dim fp16 gather, then mlp<FIRST> does W1a from h16 (fp32)
    k_gather16<<<nb_node, 256, 0, stream>>>(x16h, h16, rp, col, N);
    k_mlp<true><<<nb_tile, 256, 0, stream>>>(h16, vb, batch,
        W1a, b1a, W1b, b1b, S, bnpart, N);
    k_bnstat<<<1, 64, 0, stream>>>(bnpart, gamma, beta, ab, ab + 64, N);

    for (int l = 0; l < 4; ++l) {
        k_gather<<<nb_node, 256, 0, stream>>>(vb, aggh, rp, col,
            ab + l * 128, N);
        k_mlp<false><<<nb_tile, 256, 0, stream>>>(aggh, vb, batch,
            Wa + l * 4096, ba + l * 64, Wb + l * 4096, bb + l * 64,
            S + (size_t)(l + 1) * G * 64,
            bnpart + (size_t)(l + 1) * 32 * 128, N);
        k_bnstat<<<1, 64, 0, stream>>>(
            bnpart + (size_t)(l + 1) * 32 * 128,
            gamma + (l + 1) * 64, beta + (l + 1) * 64,
            ab + (l + 1) * 128, ab + (l + 1) * 128 + 64, N);
    }

    k_final<<<(G + 3) / 4, 256, 0, stream>>>(S, ab, cntg, fc1W, fc1b, fc2W, fc2b,
                                             (float*)d_out, G);
}